// Round 9
// baseline (28.197 us; speedup 1.0000x reference)
//
#include <hip/hip_runtime.h>
#include <math.h>

#define NP 5
#define NH 64
#define BLK 256

typedef float f32x2 __attribute__((ext_vector_type(2)));

#define LOG2E 1.44269504088896340736f
// -2y(z)*log2(e) = z*(-C_CDF0 - C_CDF1*z^2),  2y = 1.5957691*(z + 0.044715 z^3)
#define C_CDF0 2.30220840f
#define C_CDF1 0.10294324f
// d(2y)/dz = C_G2A + C_G2B*z^2
#define C_G2A 1.59576912f
#define C_G2B 0.21406460f
// phi(z)=exp2(C_PDF_A*z^2 + C_PDF_B)  (exact Gaussian, 1/sqrt(2pi) folded)
#define C_PDF_A (-0.72134752f)
#define C_PDF_B (-1.32574806f)

__global__ __launch_bounds__(BLK) void topo_kernel(
    const float* __restrict__ pillars,
    const float* __restrict__ gW1,   // [5][64]
    const float* __restrict__ gb1,   // [64]
    const float* __restrict__ gW2,   // [64]
    const float* __restrict__ gb2,   // [1]
    const float* __restrict__ gLng,  // [5]
    const float* __restrict__ gLnb,  // [5]
    const float* __restrict__ gWc,   // [12]
    const float* __restrict__ gbc,   // [1]
    float* __restrict__ out,
    int n)
{
    const int t = threadIdx.x;
    const long sidx = (long)blockIdx.x * BLK + t;
    if (sidx >= n) return;

    // LN constants (uniform scalar loads, K$-hot)
    float gam[NP], bet[NP];
    #pragma unroll
    for (int j = 0; j < NP; ++j) { gam[j] = gLng[j]; bet[j] = gLnb[j]; }

    const float* prow = pillars + sidx * NP;
    float raw[NP], p[NP], x[NP];
    #pragma unroll
    for (int j = 0; j < NP; ++j) raw[j] = prow[j];

    float mu = 0.f;
    #pragma unroll
    for (int j = 0; j < NP; ++j) {
        float v = raw[j];
        if (!(v == v)) v = 0.5f;          // NaN -> 0.5
        v = fminf(fmaxf(v, 0.f), 1.f);    // clip (handles +/-inf)
        p[j] = v; mu += v;
    }
    mu *= 0.2f;
    float var = 0.f;
    #pragma unroll
    for (int j = 0; j < NP; ++j) { float d = p[j] - mu; var += d * d; }
    var *= 0.2f;
    float inv = rsqrtf(var + 1e-5f);
    #pragma unroll
    for (int j = 0; j < NP; ++j) x[j] = (p[j] - mu) * inv * gam[j] + bet[j];

    f32x2 P[NP], X[NP];
    #pragma unroll
    for (int j = 0; j < NP; ++j) { P[j] = (f32x2){p[j], p[j]}; X[j] = (f32x2){x[j], x[j]}; }

    const f32x2 one = {1.f, 1.f}, two = {2.f, 2.f};
    const f32x2 cC0 = {-C_CDF0, -C_CDF0}, cC1 = {-C_CDF1, -C_CDF1};
    const f32x2 cGA = {C_G2A, C_G2A},     cGB = {C_G2B, C_G2B};
    const f32x2 cPA = {C_PDF_A, C_PDF_A}, cPB = {C_PDF_B, C_PDF_B};

    f32x2 V2 = {0.f,0.f}, TR = {0.f,0.f};
    f32x2 G0 = {0.f,0.f}, G1 = {0.f,0.f}, G2 = {0.f,0.f}, G3 = {0.f,0.f}, G4 = {0.f,0.f};

    #pragma unroll 8
    for (int pp = 0; pp < 32; ++pp) {
        const int k0 = 2 * pp;
        f32x2 w0 = {gW1[0*NH + k0], gW1[0*NH + k0 + 1]};
        f32x2 w1 = {gW1[1*NH + k0], gW1[1*NH + k0 + 1]};
        f32x2 w2 = {gW1[2*NH + k0], gW1[2*NH + k0 + 1]};
        f32x2 w3 = {gW1[3*NH + k0], gW1[3*NH + k0 + 1]};
        f32x2 w4 = {gW1[4*NH + k0], gW1[4*NH + k0 + 1]};
        f32x2 bb = {gb1[k0], gb1[k0 + 1]};
        f32x2 wo = {gW2[k0], gW2[k0 + 1]};

        // sw = (sum_j w_j^2) * wo  (0.2 folded into epilogue)
        f32x2 ssum = (w0*w0 + w1*w1) + (w2*w2 + w3*w3) + w4*w4;
        f32x2 sw = ssum * wo;

        // tree-form dots (depth 3)
        f32x2 z  = (P[0]*w0 + P[1]*w1) + (P[2]*w2 + P[3]*w3) + (P[4]*w4 + bb);
        f32x2 zx = (X[0]*w0 + X[1]*w1) + (X[2]*w2 + X[3]*w3) + (X[4]*w4 + bb);

        f32x2 tz = z * z;
        f32x2 tx = zx * zx;

        // --- independent trans stream 1: phi(zx), issued first ---
        f32x2 pa = tx * cPA + cPB;
        f32x2 ph;
        ph.x = __builtin_amdgcn_exp2f(pa.x);
        ph.y = __builtin_amdgcn_exp2f(pa.y);
        // trace: sw*(2 - zx^2)*phi(zx)
        TR = (sw * (two - tx)) * ph + TR;

        // --- trans stream 2: sigma(2y) via exp2 + rcp ---
        f32x2 ya = z * (tz * cC1 + cC0);
        f32x2 e;
        e.x = __builtin_amdgcn_exp2f(ya.x);
        e.y = __builtin_amdgcn_exp2f(ya.y);
        f32x2 ope = e + one;
        f32x2 s;
        s.x = __builtin_amdgcn_rcpf(ope.x);
        s.y = __builtin_amdgcn_rcpf(ope.y);

        // sigma*wo folded once; d1 = (sigma + z*sigma*(1-sigma)*g2p)*wo
        //                          = fma(z*(1-sigma)*g2p, sw_, sw_)
        f32x2 sw_  = s * wo;                     // sigma*W2
        V2 = z * sw_ + V2;                       // gelu(z)*W2
        f32x2 om  = one - s;
        f32x2 g2p = tz * cGB + cGA;              // d(2y)/dz
        f32x2 zm  = z * om;
        f32x2 d1  = (zm * g2p) * sw_ + sw_;      // gelu'(z)*W2
        G0 = w0 * d1 + G0; G1 = w1 * d1 + G1; G2 = w2 * d1 + G2;
        G3 = w3 * d1 + G3; G4 = w4 * d1 + G4;
    }

    float wcf[12];
    #pragma unroll
    for (int i = 0; i < 12; ++i) wcf[i] = gWc[i];
    const float b2v = gb2[0], bcv = gbc[0];

    float V = V2.x + V2.y + b2v;
    float emean = 0.2f * (TR.x + TR.y);

    float f[12];
    f[0] = raw[0]; f[1] = raw[1]; f[2] = raw[2]; f[3] = raw[3]; f[4] = raw[4];
    f[5] = G0.x + G0.y; f[6] = G1.x + G1.y; f[7] = G2.x + G2.y;
    f[8] = G3.x + G3.y; f[9] = G4.x + G4.y;
    f[10] = V; f[11] = emean;

    float nrm = 0.f;
    #pragma unroll
    for (int i = 0; i < 12; ++i) nrm = fmaf(f[i], f[i], nrm);
    float denom = fmaxf(sqrtf(nrm), 1e-12f);
    float dot = 0.f;
    #pragma unroll
    for (int i = 0; i < 12; ++i) dot = fmaf(f[i], wcf[i], dot);
    float sarg = dot * __builtin_amdgcn_rcpf(denom) + bcv;
    float es = __builtin_amdgcn_exp2f(-sarg * LOG2E);
    float prob = __builtin_amdgcn_rcpf(1.0f + es);
    prob = fminf(fmaxf(prob, 0.f), 1.f);
    out[sidx] = prob;
}

extern "C" void kernel_launch(void* const* d_in, const int* in_sizes, int n_in,
                              void* d_out, int out_size, void* d_ws, size_t ws_size,
                              hipStream_t stream) {
    const float* pillars = (const float*)d_in[0];
    const float* W1  = (const float*)d_in[1];
    const float* b1  = (const float*)d_in[2];
    const float* W2  = (const float*)d_in[3];
    const float* b2  = (const float*)d_in[4];
    const float* lng = (const float*)d_in[5];
    const float* lnb = (const float*)d_in[6];
    const float* Wc  = (const float*)d_in[7];
    const float* bc  = (const float*)d_in[8];
    float* out = (float*)d_out;

    const int n = in_sizes[0] / NP;     // 262144
    const int blocks = (n + BLK - 1) / BLK;   // 1024
    topo_kernel<<<blocks, BLK, 0, stream>>>(
        pillars, W1, b1, W2, b2, lng, lnb, Wc, bc, out, n);
}

// Round 10
// 20.205 us; speedup vs baseline: 1.3955x; 1.3955x over previous
//
#include <hip/hip_runtime.h>
#include <math.h>

#define NP 5
#define NH 64
#define BLK 256

typedef float f32x2 __attribute__((ext_vector_type(2)));

#define LOG2E 1.44269504088896340736f
// -2y(z)*log2(e) = z*(-C_CDF0 - C_CDF1*z^2),  2y = 1.5957691*(z + 0.044715 z^3)
#define C_CDF0 2.30220840f
#define C_CDF1 0.10294324f
// d(2y)/dz = C_G2A + C_G2B*z^2
#define C_G2A 1.59576912f
#define C_G2B 0.21406460f
// phi(z)=exp2(C_PDF_A*z^2 + C_PDF_B)  (exact Gaussian, 1/sqrt(2pi) folded)
#define C_PDF_A (-0.72134752f)
#define C_PDF_B (-1.32574806f)

__global__ __launch_bounds__(BLK) void topo_kernel(
    const float* __restrict__ pillars,
    const float* __restrict__ gW1,   // [5][64]
    const float* __restrict__ gb1,   // [64]
    const float* __restrict__ gW2,   // [64]
    const float* __restrict__ gb2,   // [1]
    const float* __restrict__ gLng,  // [5]
    const float* __restrict__ gLnb,  // [5]
    const float* __restrict__ gWc,   // [12]
    const float* __restrict__ gbc,   // [1]
    float* __restrict__ out,
    int n)
{
    const int t = threadIdx.x;
    const long sidx = (long)blockIdx.x * BLK + t;
    if (sidx >= n) return;

    // uniform constants -> scalar loads (K$-hot)
    float gam[NP], bet[NP];
    #pragma unroll
    for (int j = 0; j < NP; ++j) { gam[j] = gLng[j]; bet[j] = gLnb[j]; }

    // per-sample pillars: 5 consecutive floats, lanes stride 20B
    const float* prow = pillars + sidx * NP;
    float raw[NP], p[NP], x[NP];
    #pragma unroll
    for (int j = 0; j < NP; ++j) raw[j] = prow[j];

    float mu = 0.f;
    #pragma unroll
    for (int j = 0; j < NP; ++j) {
        float v = raw[j];
        if (!(v == v)) v = 0.5f;          // NaN -> 0.5
        v = fminf(fmaxf(v, 0.f), 1.f);    // clip (handles +/-inf)
        p[j] = v; mu += v;
    }
    mu *= 0.2f;
    float var = 0.f;
    #pragma unroll
    for (int j = 0; j < NP; ++j) { float d = p[j] - mu; var += d * d; }
    var *= 0.2f;
    float inv = rsqrtf(var + 1e-5f);
    #pragma unroll
    for (int j = 0; j < NP; ++j) x[j] = (p[j] - mu) * inv * gam[j] + bet[j];

    f32x2 P[NP], X[NP];
    #pragma unroll
    for (int j = 0; j < NP; ++j) { P[j] = (f32x2){p[j], p[j]}; X[j] = (f32x2){x[j], x[j]}; }

    const f32x2 one = {1.f, 1.f}, two = {2.f, 2.f};
    const f32x2 cC0 = {-C_CDF0, -C_CDF0}, cC1 = {-C_CDF1, -C_CDF1};
    const f32x2 cGA = {C_G2A, C_G2A},     cGB = {C_G2B, C_G2B};
    const f32x2 cPA = {C_PDF_A, C_PDF_A}, cPB = {C_PDF_B, C_PDF_B};

    f32x2 V2 = {0.f,0.f}, TR = {0.f,0.f};
    f32x2 G0 = {0.f,0.f}, G1 = {0.f,0.f}, G2 = {0.f,0.f}, G3 = {0.f,0.f}, G4 = {0.f,0.f};

    // weights at wave-uniform addresses -> compiler-scheduled s_load path
    #pragma unroll 4
    for (int pp = 0; pp < 32; ++pp) {
        const int k0 = 2 * pp;
        f32x2 w0 = {gW1[0*NH + k0], gW1[0*NH + k0 + 1]};
        f32x2 w1 = {gW1[1*NH + k0], gW1[1*NH + k0 + 1]};
        f32x2 w2 = {gW1[2*NH + k0], gW1[2*NH + k0 + 1]};
        f32x2 w3 = {gW1[3*NH + k0], gW1[3*NH + k0 + 1]};
        f32x2 w4 = {gW1[4*NH + k0], gW1[4*NH + k0 + 1]};
        f32x2 bb = {gb1[k0], gb1[k0 + 1]};
        f32x2 wo = {gW2[k0], gW2[k0 + 1]};

        // sw = (sum_j w_j^2) * wo  (0.2 folded into epilogue)
        f32x2 ssum = (w0*w0 + w1*w1) + (w2*w2 + w3*w3) + w4*w4;
        f32x2 sw = ssum * wo;

        f32x2 z  = (P[0]*w0 + P[1]*w1) + (P[2]*w2 + P[3]*w3) + (P[4]*w4 + bb);
        f32x2 zx = (X[0]*w0 + X[1]*w1) + (X[2]*w2 + X[3]*w3) + (X[4]*w4 + bb);

        f32x2 tz = z * z;
        f32x2 tx = zx * zx;

        // sigma(2y): 2 exp2 + ONE rcp (1/a,1/b = r*b, r*a with r=rcp(ab);
        // ope in (1, 5e4] so the product can't overflow)
        f32x2 ya = z * (tz * cC1 + cC0);
        f32x2 e;
        e.x = __builtin_amdgcn_exp2f(ya.x);
        e.y = __builtin_amdgcn_exp2f(ya.y);
        f32x2 ope = e + one;
        float rr = __builtin_amdgcn_rcpf(ope.x * ope.y);
        f32x2 s;
        s.x = rr * ope.y;
        s.y = rr * ope.x;

        // fold wo once: sw_ = sigma*W2; V += z*sw_;
        // d1 = (sigma + z*sigma*(1-sigma)*g2p)*W2 = fma(z*(1-sigma)*g2p, sw_, sw_)
        f32x2 sw_ = s * wo;
        V2 = z * sw_ + V2;
        f32x2 om  = one - s;
        f32x2 g2p = tz * cGB + cGA;
        f32x2 d1  = ((z * om) * g2p) * sw_ + sw_;
        G0 = w0 * d1 + G0; G1 = w1 * d1 + G1; G2 = w2 * d1 + G2;
        G3 = w3 * d1 + G3; G4 = w4 * d1 + G4;

        // trace: sw*(2 - zx^2)*phi(zx)  (phi exact, exp2 domain)
        f32x2 pa = tx * cPA + cPB;
        f32x2 ph;
        ph.x = __builtin_amdgcn_exp2f(pa.x);
        ph.y = __builtin_amdgcn_exp2f(pa.y);
        TR = (sw * (two - tx)) * ph + TR;
    }

    float wcf[12];
    #pragma unroll
    for (int i = 0; i < 12; ++i) wcf[i] = gWc[i];
    const float b2v = gb2[0], bcv = gbc[0];

    float V = V2.x + V2.y + b2v;
    float emean = 0.2f * (TR.x + TR.y);

    float f[12];
    f[0] = raw[0]; f[1] = raw[1]; f[2] = raw[2]; f[3] = raw[3]; f[4] = raw[4];
    f[5] = G0.x + G0.y; f[6] = G1.x + G1.y; f[7] = G2.x + G2.y;
    f[8] = G3.x + G3.y; f[9] = G4.x + G4.y;
    f[10] = V; f[11] = emean;

    float nrm = 0.f;
    #pragma unroll
    for (int i = 0; i < 12; ++i) nrm = fmaf(f[i], f[i], nrm);
    float denom = fmaxf(sqrtf(nrm), 1e-12f);
    float dot = 0.f;
    #pragma unroll
    for (int i = 0; i < 12; ++i) dot = fmaf(f[i], wcf[i], dot);
    float sarg = dot * __builtin_amdgcn_rcpf(denom) + bcv;
    float es = __builtin_amdgcn_exp2f(-sarg * LOG2E);
    float prob = __builtin_amdgcn_rcpf(1.0f + es);
    prob = fminf(fmaxf(prob, 0.f), 1.f);
    out[sidx] = prob;
}

extern "C" void kernel_launch(void* const* d_in, const int* in_sizes, int n_in,
                              void* d_out, int out_size, void* d_ws, size_t ws_size,
                              hipStream_t stream) {
    const float* pillars = (const float*)d_in[0];
    const float* W1  = (const float*)d_in[1];
    const float* b1  = (const float*)d_in[2];
    const float* W2  = (const float*)d_in[3];
    const float* b2  = (const float*)d_in[4];
    const float* lng = (const float*)d_in[5];
    const float* lnb = (const float*)d_in[6];
    const float* Wc  = (const float*)d_in[7];
    const float* bc  = (const float*)d_in[8];
    float* out = (float*)d_out;

    const int n = in_sizes[0] / NP;     // 262144
    const int blocks = (n + BLK - 1) / BLK;   // 1024
    topo_kernel<<<blocks, BLK, 0, stream>>>(
        pillars, W1, b1, W2, b2, lng, lnb, Wc, bc, out, n);
}

// Round 11
// 19.086 us; speedup vs baseline: 1.4774x; 1.0586x over previous
//
#include <hip/hip_runtime.h>
#include <math.h>

#define NP 5
#define NH 64
#define BLK 256

typedef float f32x2 __attribute__((ext_vector_type(2)));

#define LOG2E 1.44269504088896340736f
// -2y(z)*log2(e) = z*(-C_CDF0 - C_CDF1*z^2),  2y = 1.5957691*(z + 0.044715 z^3)
#define C_CDF0 2.30220840f
#define C_CDF1 0.10294324f
// d(2y)/dz = C_G2A + C_G2B*z^2
#define C_G2A 1.59576912f
#define C_G2B 0.21406460f
// phi(z)=exp2(C_PDF_A*z^2 + C_PDF_B)  (exact Gaussian, 1/sqrt(2pi) folded)
#define C_PDF_A (-0.72134752f)
#define C_PDF_B (-1.32574806f)

__global__ __launch_bounds__(BLK) void topo_kernel(
    const float* __restrict__ pillars,
    const float* __restrict__ gW1,   // [5][64]
    const float* __restrict__ gb1,   // [64]
    const float* __restrict__ gW2,   // [64]
    const float* __restrict__ gb2,   // [1]
    const float* __restrict__ gLng,  // [5]
    const float* __restrict__ gLnb,  // [5]
    const float* __restrict__ gWc,   // [12]
    const float* __restrict__ gbc,   // [1]
    float* __restrict__ out,
    int n)
{
    const int t = threadIdx.x;
    const long sidx = (long)blockIdx.x * BLK + t;
    if (sidx >= n) return;

    // uniform constants -> scalar loads (K$-hot)
    float gam[NP], bet[NP], wcf[12];
    #pragma unroll
    for (int j = 0; j < NP; ++j) { gam[j] = gLng[j]; bet[j] = gLnb[j]; }
    #pragma unroll
    for (int i = 0; i < 12; ++i) wcf[i] = gWc[i];
    const float b2v = gb2[0], bcv = gbc[0];

    // per-sample pillars: 5 consecutive floats, lanes stride 20B (L1-coalesced)
    const float* prow = pillars + sidx * NP;
    float raw[NP], p[NP], x[NP];
    #pragma unroll
    for (int j = 0; j < NP; ++j) raw[j] = prow[j];

    float mu = 0.f;
    #pragma unroll
    for (int j = 0; j < NP; ++j) {
        float v = raw[j];
        if (!(v == v)) v = 0.5f;          // NaN -> 0.5
        v = fminf(fmaxf(v, 0.f), 1.f);    // clip (handles +/-inf)
        p[j] = v; mu += v;
    }
    mu *= 0.2f;
    float var = 0.f;
    #pragma unroll
    for (int j = 0; j < NP; ++j) { float d = p[j] - mu; var += d * d; }
    var *= 0.2f;
    float inv = rsqrtf(var + 1e-5f);
    #pragma unroll
    for (int j = 0; j < NP; ++j) x[j] = (p[j] - mu) * inv * gam[j] + bet[j];

    f32x2 P[NP], X[NP];
    #pragma unroll
    for (int j = 0; j < NP; ++j) { P[j] = (f32x2){p[j], p[j]}; X[j] = (f32x2){x[j], x[j]}; }

    const f32x2 one = {1.f, 1.f}, two = {2.f, 2.f};
    const f32x2 cC0 = {-C_CDF0, -C_CDF0}, cC1 = {-C_CDF1, -C_CDF1};
    const f32x2 cGA = {C_G2A, C_G2A},     cGB = {C_G2B, C_G2B};
    const f32x2 cPA = {C_PDF_A, C_PDF_A}, cPB = {C_PDF_B, C_PDF_B};

    f32x2 V2 = {0.f,0.f}, TR = {0.f,0.f};
    f32x2 G0 = {0.f,0.f}, G1 = {0.f,0.f}, G2 = {0.f,0.f}, G3 = {0.f,0.f}, G4 = {0.f,0.f};

    // weights read at wave-uniform addresses -> compiler emits s_load_*,
    // schedules/batches them itself (no LDS, no syncthreads, no asm drains)
    #pragma unroll 4
    for (int pp = 0; pp < 32; ++pp) {
        const int k0 = 2 * pp;
        f32x2 w0 = {gW1[0*NH + k0], gW1[0*NH + k0 + 1]};
        f32x2 w1 = {gW1[1*NH + k0], gW1[1*NH + k0 + 1]};
        f32x2 w2 = {gW1[2*NH + k0], gW1[2*NH + k0 + 1]};
        f32x2 w3 = {gW1[3*NH + k0], gW1[3*NH + k0 + 1]};
        f32x2 w4 = {gW1[4*NH + k0], gW1[4*NH + k0 + 1]};
        f32x2 bb = {gb1[k0], gb1[k0 + 1]};
        f32x2 wo = {gW2[k0], gW2[k0 + 1]};

        // sw = (sum_j w_j^2) * wo   (0.2 folded into epilogue)
        f32x2 ssum = w0*w0 + (w1*w1 + (w2*w2 + (w3*w3 + w4*w4)));
        f32x2 sw = ssum * wo;

        f32x2 z  = P[0]*w0 + (P[1]*w1 + (P[2]*w2 + (P[3]*w3 + (P[4]*w4 + bb))));
        f32x2 zx = X[0]*w0 + (X[1]*w1 + (X[2]*w2 + (X[3]*w3 + (X[4]*w4 + bb))));

        f32x2 tz = z * z;
        f32x2 tx = zx * zx;

        // sigma(2y) via exp2
        f32x2 ya = z * (tz * cC1 + cC0);
        f32x2 e;
        e.x = __builtin_amdgcn_exp2f(ya.x);
        e.y = __builtin_amdgcn_exp2f(ya.y);
        f32x2 ope = e + one;
        f32x2 s;
        s.x = __builtin_amdgcn_rcpf(ope.x);
        s.y = __builtin_amdgcn_rcpf(ope.y);

        V2 = (z * s) * wo + V2;                       // gelu(z)*W2
        f32x2 u   = s - s * s;                        // sigma*(1-sigma)
        f32x2 g2p = tz * cGB + cGA;                   // d(2y)/dz
        f32x2 d1  = ((z * u) * g2p + s) * wo;         // gelu'(z)*W2
        G0 = w0 * d1 + G0; G1 = w1 * d1 + G1; G2 = w2 * d1 + G2;
        G3 = w3 * d1 + G3; G4 = w4 * d1 + G4;

        // trace: sw*(2 - zx^2)*phi(zx)  (phi exact, exp2 domain)
        f32x2 pa = tx * cPA + cPB;
        f32x2 ph;
        ph.x = __builtin_amdgcn_exp2f(pa.x);
        ph.y = __builtin_amdgcn_exp2f(pa.y);
        TR = (sw * (two - tx)) * ph + TR;
    }

    float V = V2.x + V2.y + b2v;
    float emean = 0.2f * (TR.x + TR.y);

    float f[12];
    f[0] = raw[0]; f[1] = raw[1]; f[2] = raw[2]; f[3] = raw[3]; f[4] = raw[4];
    f[5] = G0.x + G0.y; f[6] = G1.x + G1.y; f[7] = G2.x + G2.y;
    f[8] = G3.x + G3.y; f[9] = G4.x + G4.y;
    f[10] = V; f[11] = emean;

    float nrm = 0.f;
    #pragma unroll
    for (int i = 0; i < 12; ++i) nrm = fmaf(f[i], f[i], nrm);
    float denom = fmaxf(sqrtf(nrm), 1e-12f);
    float dot = 0.f;
    #pragma unroll
    for (int i = 0; i < 12; ++i) dot = fmaf(f[i], wcf[i], dot);
    float sarg = dot * __builtin_amdgcn_rcpf(denom) + bcv;
    float es = __builtin_amdgcn_exp2f(-sarg * LOG2E);
    float prob = __builtin_amdgcn_rcpf(1.0f + es);
    prob = fminf(fmaxf(prob, 0.f), 1.f);
    out[sidx] = prob;
}

extern "C" void kernel_launch(void* const* d_in, const int* in_sizes, int n_in,
                              void* d_out, int out_size, void* d_ws, size_t ws_size,
                              hipStream_t stream) {
    const float* pillars = (const float*)d_in[0];
    const float* W1  = (const float*)d_in[1];
    const float* b1  = (const float*)d_in[2];
    const float* W2  = (const float*)d_in[3];
    const float* b2  = (const float*)d_in[4];
    const float* lng = (const float*)d_in[5];
    const float* lnb = (const float*)d_in[6];
    const float* Wc  = (const float*)d_in[7];
    const float* bc  = (const float*)d_in[8];
    float* out = (float*)d_out;

    const int n = in_sizes[0] / NP;     // 262144
    const int blocks = (n + BLK - 1) / BLK;   // 1024
    topo_kernel<<<blocks, BLK, 0, stream>>>(
        pillars, W1, b1, W2, b2, lng, lnb, Wc, bc, out, n);
}